// Round 2
// baseline (210.609 us; speedup 1.0000x reference)
//
#include <hip/hip_runtime.h>

// Problem constants (from reference setup_inputs)
#define BB   64          // batch
#define SS   512         // seq len
#define HH   768         // hidden dim
#define WW   256         // MAX_WORD_LEN (words per batch)
#define WE   300         // word-embedding dim
#define OUTD (HH + WE)   // 1068 output feature dim

// ---------------------------------------------------------------------------
// Kernel A: precompute segment boundaries.
// bounds[b*(WW+1) + w] = lower_bound(token_ids[b,:], w)  for w in [0,WW]
// token_ids rows are sorted, values in [0,WW). bounds[b][WW] = SS.
// 64 blocks x 256 threads; each thread does one 9-step binary search over a
// 2 KB row (L1/L2 resident). ~2 us total.
// ---------------------------------------------------------------------------
__global__ __launch_bounds__(256)
void seg_bounds_kernel(const int* __restrict__ token_ids,  // [B, S]
                       int* __restrict__ bounds)           // [B, WW+1]
{
    const int b = blockIdx.x;
    const int w = threadIdx.x;
    const int* tk = token_ids + b * SS;

    int l = 0, r = SS;
    while (l < r) { int m = (l + r) >> 1; if (tk[m] < w) l = m + 1; else r = m; }
    bounds[b * (WW + 1) + w] = l;
    if (w == 0) bounds[b * (WW + 1) + WW] = SS;
}

// ---------------------------------------------------------------------------
// Kernel B: one block per (b, w). Waves 0-2 (192 threads) compute the
// segment-mean of hidden over rows [lo,hi); wave 3 copies the w2v row.
// Segment bounds come from d_ws -> just 2 uniform scalar loads instead of
// ~18 dependent binary-search loads per block.
// ---------------------------------------------------------------------------
__global__ __launch_bounds__(256)
void EmbeddingsModule_45311904973549_kernel(
    const float* __restrict__ hidden,     // [B, S, H]
    const float* __restrict__ w2v,        // [VOCAB, WE]
    const int*   __restrict__ bounds,     // [B, WW+1]
    const int*   __restrict__ word_ids,   // [B, W] in [0,VOCAB)
    float*       __restrict__ out)        // [B, W, OUTD]
{
    const int bw  = blockIdx.x;       // 0 .. B*W-1
    const int b   = bw >> 8;          // / WW
    const int w   = bw & (WW - 1);    // % WW
    const int tid = threadIdx.x;

    float* orow = out + (size_t)bw * OUTD;

    if (tid < 192) {
        const int lo = bounds[b * (WW + 1) + w];
        const int hi = bounds[b * (WW + 1) + w + 1];
        const int   cnt = hi - lo;
        const float inv = (cnt > 0) ? (1.0f / (float)cnt) : 0.0f;

        // mean of hidden[b, lo:hi, tid*4 : tid*4+4]
        const float4* hrow = (const float4*)(hidden + (size_t)b * SS * HH);
        float4 acc = make_float4(0.f, 0.f, 0.f, 0.f);
        for (int s = lo; s < hi; ++s) {
            float4 v = hrow[(size_t)s * (HH / 4) + tid];
            acc.x += v.x; acc.y += v.y; acc.z += v.z; acc.w += v.w;
        }
        acc.x *= inv; acc.y *= inv; acc.z *= inv; acc.w *= inv;
        ((float4*)orow)[tid] = acc;     // out[b,w, 0:768]
    } else {
        // w2v gather: 75 float4s with 64 threads (j and j+64)
        const int     wid  = word_ids[bw];
        const float4* wrow = (const float4*)(w2v + (size_t)wid * WE);
        float4*       grow = (float4*)(orow + HH);   // out[b,w, 768:1068]
        for (int j = tid - 192; j < WE / 4; j += 64) {
            grow[j] = wrow[j];
        }
    }
}

extern "C" void kernel_launch(void* const* d_in, const int* in_sizes, int n_in,
                              void* d_out, int out_size, void* d_ws, size_t ws_size,
                              hipStream_t stream) {
    const float* hidden    = (const float*)d_in[0];
    const float* w2v       = (const float*)d_in[1];
    const int*   token_ids = (const int*)d_in[2];
    const int*   word_ids  = (const int*)d_in[3];
    float*       out       = (float*)d_out;
    int*         bounds    = (int*)d_ws;   // B*(WW+1) ints = 65.8 KB

    seg_bounds_kernel<<<BB, 256, 0, stream>>>(token_ids, bounds);
    EmbeddingsModule_45311904973549_kernel<<<BB * WW, 256, 0, stream>>>(
        hidden, w2v, bounds, word_ids, out);
}